// Round 1
// baseline (203.836 us; speedup 1.0000x reference)
//
#include <hip/hip_runtime.h>
#include <hip/hip_bf16.h>
#include <math.h>

// Problem constants (from reference)
#define B_ 8
#define T_ 1024
#define D_ 256
#define K_ 100
#define G_ 2
#define V_ 320
#define NT_ 101            // 1 positive + K negatives
#define TEMP_ 0.1f
#define DIV_W_ 0.1f
#define L2_W_ 10.0f
#define DIV_EPS_ 1e-7f
#define COS_EPS_ 1e-8f

// ws layout (floats):
//   [0]          loss_c accumulator (sum of -logp0 over masked positions)
//   [1]          sum of quantized^2
//   [2 .. 2+640) avg-prob accumulators (G*V)
//   [644]        mask-layout flag (int): 0=int32, 1=float32, 2=bool/byte
#define WS_FLAG_IDX 644

// ---------------------------------------------------------------------------
// Detect how the boolean mask was materialized on device.
// int32 0/1 -> words in {0,1}; float32 0/1 -> words in {0,0x3F800000};
// bool bytes -> words are packed 0/1 bytes (e.g. 0x01000101).
// Deterministic per input; runs every call (graph-capture safe).
// ---------------------------------------------------------------------------
__global__ void detect_mask_kernel(const unsigned int* __restrict__ mw,
                                   int* __restrict__ flag) {
    __shared__ int sA, sB;
    if (threadIdx.x == 0) { sA = 0; sB = 0; }
    __syncthreads();
    int a = 0, b = 0;
    for (int i = threadIdx.x; i < (B_ * T_) / 4; i += blockDim.x) {
        unsigned int w = mw[i];
        a |= (w > 1u) ? 1 : 0;
        b |= (w != 0u && w != 0x3F800000u) ? 1 : 0;
    }
    if (a) atomicOr(&sA, 1);
    if (b) atomicOr(&sB, 1);
    __syncthreads();
    if (threadIdx.x == 0) {
        *flag = (!sA) ? 0 : ((!sB) ? 1 : 2);
    }
}

// ---------------------------------------------------------------------------
// Contrastive loss: one block per (b,t). 16 lane-groups of 16 lanes; each
// group handles targets k = grp, grp+16, ... Each lane holds an interleaved
// float4 slice of pred (d = lane*4 + i*64) -> coalesced gathers.
// ---------------------------------------------------------------------------
__global__ __launch_bounds__(256) void contrastive_kernel(
    const float* __restrict__ quant,
    const float* __restrict__ ctx,
    const int* __restrict__ negidx,
    const void* __restrict__ maskp,
    const int* __restrict__ flagp,
    float* __restrict__ out_acc)
{
    const int bt = blockIdx.x;
    const int b = bt >> 10;          // T_ = 1024
    const int t = bt & (T_ - 1);

    const int flag = *flagp;
    bool m;
    if (flag == 2)      m = ((const unsigned char*)maskp)[bt] != 0;
    else if (flag == 1) m = ((const float*)maskp)[bt] != 0.0f;
    else                m = ((const int*)maskp)[bt] != 0;
    if (!m) return;   // uniform across block: safe w.r.t. barriers

    __shared__ float s_logits[NT_ + 3];

    const int tid = threadIdx.x;
    const int lane16 = tid & 15;
    const int grp = tid >> 4;        // 0..15

    const float4* pred4 = (const float4*)(ctx + (size_t)bt * D_);
    const float4 p0 = pred4[lane16];
    const float4 p1 = pred4[lane16 + 16];
    const float4 p2 = pred4[lane16 + 32];
    const float4 p3 = pred4[lane16 + 48];

    float pn2 = p0.x*p0.x + p0.y*p0.y + p0.z*p0.z + p0.w*p0.w
              + p1.x*p1.x + p1.y*p1.y + p1.z*p1.z + p1.w*p1.w
              + p2.x*p2.x + p2.y*p2.y + p2.z*p2.z + p2.w*p2.w
              + p3.x*p3.x + p3.y*p3.y + p3.z*p3.z + p3.w*p3.w;
#pragma unroll
    for (int s = 8; s >= 1; s >>= 1) pn2 += __shfl_xor(pn2, s);
    const float pn = sqrtf(pn2);

    const float4* qb = (const float4*)(quant + (size_t)b * T_ * D_);
    const int* nrow = negidx + (size_t)bt * K_;

    for (int k = grp; k < NT_; k += 16) {
        const int idx = (k == 0) ? t : nrow[k - 1];
        const float4* trow = qb + (size_t)idx * (D_ / 4);
        const float4 a0 = trow[lane16];
        const float4 a1 = trow[lane16 + 16];
        const float4 a2 = trow[lane16 + 32];
        const float4 a3 = trow[lane16 + 48];

        float dt  = p0.x*a0.x + p0.y*a0.y + p0.z*a0.z + p0.w*a0.w
                  + p1.x*a1.x + p1.y*a1.y + p1.z*a1.z + p1.w*a1.w
                  + p2.x*a2.x + p2.y*a2.y + p2.z*a2.z + p2.w*a2.w
                  + p3.x*a3.x + p3.y*a3.y + p3.z*a3.z + p3.w*a3.w;
        float tn2 = a0.x*a0.x + a0.y*a0.y + a0.z*a0.z + a0.w*a0.w
                  + a1.x*a1.x + a1.y*a1.y + a1.z*a1.z + a1.w*a1.w
                  + a2.x*a2.x + a2.y*a2.y + a2.z*a2.z + a2.w*a2.w
                  + a3.x*a3.x + a3.y*a3.y + a3.z*a3.z + a3.w*a3.w;
#pragma unroll
        for (int s = 8; s >= 1; s >>= 1) {
            dt  += __shfl_xor(dt, s);
            tn2 += __shfl_xor(tn2, s);
        }
        if (lane16 == 0) {
            const float cosv = dt / fmaxf(pn * sqrtf(tn2), COS_EPS_);
            s_logits[k] = (k > 0 && idx == t) ? -1e30f : cosv * (1.0f / TEMP_);
        }
    }
    __syncthreads();

    if (tid < 64) {
        const float l0 = (tid < NT_) ? s_logits[tid] : -1e30f;
        const float l1 = (tid + 64 < NT_) ? s_logits[tid + 64] : -1e30f;
        float mx = fmaxf(l0, l1);
#pragma unroll
        for (int s = 32; s >= 1; s >>= 1) mx = fmaxf(mx, __shfl_xor(mx, s));
        float sum = __expf(l0 - mx) + __expf(l1 - mx);
#pragma unroll
        for (int s = 32; s >= 1; s >>= 1) sum += __shfl_xor(sum, s);
        if (tid == 0) {
            const float logp0 = s_logits[0] - (mx + __logf(sum));
            atomicAdd(out_acc, -logp0);
        }
    }
}

// ---------------------------------------------------------------------------
// Codebook softmax + average-prob accumulation. One wave per row (V=320 ->
// 5 floats/lane). Register-accumulate per wave, LDS-combine, one global
// atomic pass per block.
// ---------------------------------------------------------------------------
__global__ __launch_bounds__(512) void codebook_kernel(
    const float* __restrict__ logits, float* __restrict__ avg_acc)
{
    __shared__ float acc[G_ * V_];
    const int tid = threadIdx.x;
    for (int i = tid; i < G_ * V_; i += 512) acc[i] = 0.0f;
    __syncthreads();

    const int lane = tid & 63;
    const int wave = tid >> 6;
    float r0[5] = {0, 0, 0, 0, 0};
    float r1[5] = {0, 0, 0, 0, 0};
    const int nrows = B_ * T_ * G_;

    for (int r = blockIdx.x * 8 + wave; r < nrows; r += gridDim.x * 8) {
        const float* row = logits + (size_t)r * V_;
        float v[5];
#pragma unroll
        for (int i = 0; i < 5; i++) v[i] = row[lane + 64 * i];
        float mx = fmaxf(fmaxf(fmaxf(v[0], v[1]), fmaxf(v[2], v[3])), v[4]);
#pragma unroll
        for (int s = 32; s >= 1; s >>= 1) mx = fmaxf(mx, __shfl_xor(mx, s));
        float e[5], sum = 0.0f;
#pragma unroll
        for (int i = 0; i < 5; i++) { e[i] = __expf(v[i] - mx); sum += e[i]; }
#pragma unroll
        for (int s = 32; s >= 1; s >>= 1) sum += __shfl_xor(sum, s);
        const float inv = 1.0f / sum;
        if (r & 1) {
#pragma unroll
            for (int i = 0; i < 5; i++) r1[i] += e[i] * inv;
        } else {
#pragma unroll
            for (int i = 0; i < 5; i++) r0[i] += e[i] * inv;
        }
    }
#pragma unroll
    for (int i = 0; i < 5; i++) {
        atomicAdd(&acc[0 * V_ + lane + 64 * i], r0[i]);
        atomicAdd(&acc[1 * V_ + lane + 64 * i], r1[i]);
    }
    __syncthreads();
    for (int i = tid; i < G_ * V_; i += 512) atomicAdd(&avg_acc[i], acc[i]);
}

// ---------------------------------------------------------------------------
// Sum of squares of quantized features.
// ---------------------------------------------------------------------------
__global__ __launch_bounds__(256) void l2_kernel(
    const float* __restrict__ q, float* __restrict__ acc)
{
    const int n4 = (B_ * T_ * D_) / 4;
    const float4* q4 = (const float4*)q;
    float s = 0.0f;
    for (int i = blockIdx.x * blockDim.x + threadIdx.x; i < n4;
         i += gridDim.x * blockDim.x) {
        const float4 v = q4[i];
        s += v.x * v.x + v.y * v.y + v.z * v.z + v.w * v.w;
    }
#pragma unroll
    for (int sft = 32; sft >= 1; sft >>= 1) s += __shfl_xor(s, sft);
    if ((threadIdx.x & 63) == 0) atomicAdd(acc, s);
}

// ---------------------------------------------------------------------------
// Finalize: entropy/perplexity per group, combine all three losses.
// ---------------------------------------------------------------------------
__global__ void finalize_kernel(const float* __restrict__ ws,
                                float* __restrict__ out)
{
    const int lane = threadIdx.x;   // 64 threads
    const float* avg = ws + 2;
    float e0 = 0.0f, e1 = 0.0f;
#pragma unroll
    for (int i = 0; i < 5; i++) {
        const float a0 = avg[0 * V_ + lane + 64 * i] * (1.0f / (B_ * T_));
        const float a1 = avg[1 * V_ + lane + 64 * i] * (1.0f / (B_ * T_));
        e0 -= a0 * __logf(a0 + DIV_EPS_);
        e1 -= a1 * __logf(a1 + DIV_EPS_);
    }
#pragma unroll
    for (int s = 32; s >= 1; s >>= 1) {
        e0 += __shfl_xor(e0, s);
        e1 += __shfl_xor(e1, s);
    }
    if (lane == 0) {
        const float loss_d = ((float)V_ - __expf(e0)) + ((float)V_ - __expf(e1));
        const float loss_l2 = ws[1] / (float)(B_ * T_ * D_);
        out[0] = ws[0] + DIV_W_ * loss_d + L2_W_ * loss_l2;
    }
}

extern "C" void kernel_launch(void* const* d_in, const int* in_sizes, int n_in,
                              void* d_out, int out_size, void* d_ws, size_t ws_size,
                              hipStream_t stream) {
    const float* quant = (const float*)d_in[0];
    const float* ctx   = (const float*)d_in[1];
    const float* cb    = (const float*)d_in[2];
    const int*   nidx  = (const int*)d_in[3];
    const void*  mask  = d_in[4];
    float* ws  = (float*)d_ws;
    float* out = (float*)d_out;

    // zero accumulators [0 .. 2+G*V)
    hipMemsetAsync(d_ws, 0, (2 + G_ * V_) * sizeof(float), stream);

    detect_mask_kernel<<<1, 256, 0, stream>>>((const unsigned int*)mask,
                                              (int*)(ws + WS_FLAG_IDX));
    contrastive_kernel<<<B_ * T_, 256, 0, stream>>>(
        quant, ctx, nidx, mask, (const int*)(ws + WS_FLAG_IDX), ws);
    codebook_kernel<<<256, 512, 0, stream>>>(cb, ws + 2);
    l2_kernel<<<512, 256, 0, stream>>>(quant, ws + 1);
    finalize_kernel<<<1, 64, 0, stream>>>(ws, out);
}

// Round 2
// 188.815 us; speedup vs baseline: 1.0796x; 1.0796x over previous
//
#include <hip/hip_runtime.h>
#include <hip/hip_bf16.h>
#include <math.h>

// Problem constants (from reference)
#define B_ 8
#define T_ 1024
#define D_ 256
#define K_ 100
#define G_ 2
#define V_ 320
#define NT_ 101            // 1 positive + K negatives
#define TEMP_ 0.1f
#define DIV_W_ 0.1f
#define L2_W_ 10.0f
#define DIV_EPS_ 1e-7f
#define COS_EPS_ 1e-8f

// ws layout (floats):
//   [0]              loss_c accumulator
//   [1]              sum of quantized^2
//   [2 .. 642)       avg-prob accumulators (G*V = 640)
//   [644]            mask-layout flag (int)
//   [1024 .. 9216)   qnorm[B*T]
//   [9216 .. 17408)  cnorm[B*T]
#define WS_FLAG_IDX 644
#define WS_QNORM    1024
#define WS_CNORM    (1024 + B_ * T_)

// ---------------------------------------------------------------------------
// Detect how the boolean mask was materialized on device.
// ---------------------------------------------------------------------------
__global__ void detect_mask_kernel(const unsigned int* __restrict__ mw,
                                   int* __restrict__ flag) {
    __shared__ int sA, sB;
    if (threadIdx.x == 0) { sA = 0; sB = 0; }
    __syncthreads();
    int a = 0, b = 0;
    for (int i = threadIdx.x; i < (B_ * T_) / 4; i += blockDim.x) {
        unsigned int w = mw[i];
        a |= (w > 1u) ? 1 : 0;
        b |= (w != 0u && w != 0x3F800000u) ? 1 : 0;
    }
    if (a) atomicOr(&sA, 1);
    if (b) atomicOr(&sB, 1);
    __syncthreads();
    if (threadIdx.x == 0) {
        *flag = (!sA) ? 0 : ((!sB) ? 1 : 2);
    }
}

// ---------------------------------------------------------------------------
// Per-row norms of quant and ctx + global sum-of-squares of quant.
// One wave per row per iteration; 512 blocks x 256 thr = 2048 waves.
// ---------------------------------------------------------------------------
__global__ __launch_bounds__(256) void norms_kernel(
    const float* __restrict__ q, const float* __restrict__ c,
    float* __restrict__ qnorm, float* __restrict__ cnorm,
    float* __restrict__ ssq_acc)
{
    const int lane = threadIdx.x & 63;
    const int wavein = threadIdx.x >> 6;
    const int wave = blockIdx.x * 4 + wavein;
    const int nwaves = gridDim.x * 4;
    float ssq = 0.0f;

    for (int r = wave; r < B_ * T_; r += nwaves) {
        const float4 v = ((const float4*)(q + (size_t)r * D_))[lane];
        float s = v.x * v.x + v.y * v.y + v.z * v.z + v.w * v.w;
        ssq += s;                      // per-lane partial (pre-reduce)
        const float4 w = ((const float4*)(c + (size_t)r * D_))[lane];
        float s2 = w.x * w.x + w.y * w.y + w.z * w.z + w.w * w.w;
#pragma unroll
        for (int sh = 32; sh >= 1; sh >>= 1) {
            s  += __shfl_xor(s, sh);
            s2 += __shfl_xor(s2, sh);
        }
        if (lane == 0) {
            qnorm[r] = sqrtf(s);
            cnorm[r] = sqrtf(s2);
        }
    }
#pragma unroll
    for (int sh = 32; sh >= 1; sh >>= 1) ssq += __shfl_xor(ssq, sh);
    __shared__ float ls[4];
    if (lane == 0) ls[wavein] = ssq;
    __syncthreads();
    if (threadIdx.x == 0)
        atomicAdd(ssq_acc, ls[0] + ls[1] + ls[2] + ls[3]);
}

// ---------------------------------------------------------------------------
// Contrastive loss: one block per (b,t). 16 lane-groups of 16 lanes; each
// group handles 2 targets per iteration (k, k+16) for ILP. Norms are
// precomputed -> inner loop is dot-product only.
// ---------------------------------------------------------------------------
__global__ __launch_bounds__(256) void contrastive_kernel(
    const float* __restrict__ quant,
    const float* __restrict__ ctx,
    const int* __restrict__ negidx,
    const void* __restrict__ maskp,
    const int* __restrict__ flagp,
    const float* __restrict__ qnorm,
    const float* __restrict__ cnorm,
    float* __restrict__ out_acc)
{
    const int bt = blockIdx.x;
    const int b = bt >> 10;          // T_ = 1024
    const int t = bt & (T_ - 1);

    const int flag = *flagp;
    bool m;
    if (flag == 2)      m = ((const unsigned char*)maskp)[bt] != 0;
    else if (flag == 1) m = ((const float*)maskp)[bt] != 0.0f;
    else                m = ((const int*)maskp)[bt] != 0;
    if (!m) return;   // uniform across block: safe w.r.t. barriers

    __shared__ float s_logits[NT_ + 3];

    const int tid = threadIdx.x;
    const int lane16 = tid & 15;
    const int grp = tid >> 4;        // 0..15

    const float4* pred4 = (const float4*)(ctx + (size_t)bt * D_);
    const float4 p0 = pred4[lane16];
    const float4 p1 = pred4[lane16 + 16];
    const float4 p2 = pred4[lane16 + 32];
    const float4 p3 = pred4[lane16 + 48];
    const float pn = cnorm[bt];

    const float4* qb = (const float4*)(quant + (size_t)b * T_ * D_);
    const float* qn = qnorm + b * T_;
    const int* nrow = negidx + (size_t)bt * K_;

    for (int k = grp; k < NT_; k += 32) {
        const int k2 = k + 16;
        const bool has1 = (k2 < NT_);
        const int idx0 = (k == 0) ? t : nrow[k - 1];
        const int idx1 = has1 ? nrow[k2 - 1] : idx0;   // k2 >= 16, never pos

        const float tn0 = qn[idx0];
        const float tn1 = qn[idx1];

        const float4* r0p = qb + (size_t)idx0 * (D_ / 4);
        const float4* r1p = qb + (size_t)idx1 * (D_ / 4);
        const float4 a0 = r0p[lane16];
        const float4 a1 = r0p[lane16 + 16];
        const float4 a2 = r0p[lane16 + 32];
        const float4 a3 = r0p[lane16 + 48];
        const float4 b0 = r1p[lane16];
        const float4 b1 = r1p[lane16 + 16];
        const float4 b2 = r1p[lane16 + 32];
        const float4 b3 = r1p[lane16 + 48];

        float dt0 = p0.x*a0.x + p0.y*a0.y + p0.z*a0.z + p0.w*a0.w
                  + p1.x*a1.x + p1.y*a1.y + p1.z*a1.z + p1.w*a1.w
                  + p2.x*a2.x + p2.y*a2.y + p2.z*a2.z + p2.w*a2.w
                  + p3.x*a3.x + p3.y*a3.y + p3.z*a3.z + p3.w*a3.w;
        float dt1 = p0.x*b0.x + p0.y*b0.y + p0.z*b0.z + p0.w*b0.w
                  + p1.x*b1.x + p1.y*b1.y + p1.z*b1.z + p1.w*b1.w
                  + p2.x*b2.x + p2.y*b2.y + p2.z*b2.z + p2.w*b2.w
                  + p3.x*b3.x + p3.y*b3.y + p3.z*b3.z + p3.w*b3.w;
#pragma unroll
        for (int s = 8; s >= 1; s >>= 1) {
            dt0 += __shfl_xor(dt0, s);
            dt1 += __shfl_xor(dt1, s);
        }
        if (lane16 == 0) {
            const float c0 = dt0 / fmaxf(pn * tn0, COS_EPS_);
            s_logits[k] = (k > 0 && idx0 == t) ? -1e30f : c0 * (1.0f / TEMP_);
            if (has1) {
                const float c1 = dt1 / fmaxf(pn * tn1, COS_EPS_);
                s_logits[k2] = (idx1 == t) ? -1e30f : c1 * (1.0f / TEMP_);
            }
        }
    }
    __syncthreads();

    if (tid < 64) {
        const float l0 = (tid < NT_) ? s_logits[tid] : -1e30f;
        const float l1 = (tid + 64 < NT_) ? s_logits[tid + 64] : -1e30f;
        float mx = fmaxf(l0, l1);
#pragma unroll
        for (int s = 32; s >= 1; s >>= 1) mx = fmaxf(mx, __shfl_xor(mx, s));
        float sum = __expf(l0 - mx) + __expf(l1 - mx);
#pragma unroll
        for (int s = 32; s >= 1; s >>= 1) sum += __shfl_xor(sum, s);
        if (tid == 0) {
            const float logp0 = s_logits[0] - (mx + __logf(sum));
            atomicAdd(out_acc, -logp0);
        }
    }
}

// ---------------------------------------------------------------------------
// Codebook softmax + average-prob accumulation. 512 blocks x 512 thr =
// 4096 waves (16/CU); each wave handles 4 rows (V=320 -> 5 floats/lane).
// ---------------------------------------------------------------------------
__global__ __launch_bounds__(512) void codebook_kernel(
    const float* __restrict__ logits, float* __restrict__ avg_acc)
{
    __shared__ float acc[G_ * V_];
    const int tid = threadIdx.x;
    for (int i = tid; i < G_ * V_; i += 512) acc[i] = 0.0f;
    __syncthreads();

    const int lane = tid & 63;
    const int wave = tid >> 6;
    float r0[5] = {0, 0, 0, 0, 0};
    float r1[5] = {0, 0, 0, 0, 0};
    const int nrows = B_ * T_ * G_;

    for (int r = blockIdx.x * 8 + wave; r < nrows; r += gridDim.x * 8) {
        const float* row = logits + (size_t)r * V_;
        float v[5];
#pragma unroll
        for (int i = 0; i < 5; i++) v[i] = row[lane + 64 * i];
        float mx = fmaxf(fmaxf(fmaxf(v[0], v[1]), fmaxf(v[2], v[3])), v[4]);
#pragma unroll
        for (int s = 32; s >= 1; s >>= 1) mx = fmaxf(mx, __shfl_xor(mx, s));
        float e[5], sum = 0.0f;
#pragma unroll
        for (int i = 0; i < 5; i++) { e[i] = __expf(v[i] - mx); sum += e[i]; }
#pragma unroll
        for (int s = 32; s >= 1; s >>= 1) sum += __shfl_xor(sum, s);
        const float inv = 1.0f / sum;
        if (r & 1) {   // r-parity constant per wave (even strides)
#pragma unroll
            for (int i = 0; i < 5; i++) r1[i] += e[i] * inv;
        } else {
#pragma unroll
            for (int i = 0; i < 5; i++) r0[i] += e[i] * inv;
        }
    }
#pragma unroll
    for (int i = 0; i < 5; i++) {
        atomicAdd(&acc[0 * V_ + lane + 64 * i], r0[i]);
        atomicAdd(&acc[1 * V_ + lane + 64 * i], r1[i]);
    }
    __syncthreads();
    for (int i = tid; i < G_ * V_; i += 512) atomicAdd(&avg_acc[i], acc[i]);
}

// ---------------------------------------------------------------------------
// Finalize: entropy/perplexity per group, combine all three losses.
// ---------------------------------------------------------------------------
__global__ void finalize_kernel(const float* __restrict__ ws,
                                float* __restrict__ out)
{
    const int lane = threadIdx.x;   // 64 threads
    const float* avg = ws + 2;
    float e0 = 0.0f, e1 = 0.0f;
#pragma unroll
    for (int i = 0; i < 5; i++) {
        const float a0 = avg[0 * V_ + lane + 64 * i] * (1.0f / (B_ * T_));
        const float a1 = avg[1 * V_ + lane + 64 * i] * (1.0f / (B_ * T_));
        e0 -= a0 * __logf(a0 + DIV_EPS_);
        e1 -= a1 * __logf(a1 + DIV_EPS_);
    }
#pragma unroll
    for (int s = 32; s >= 1; s >>= 1) {
        e0 += __shfl_xor(e0, s);
        e1 += __shfl_xor(e1, s);
    }
    if (lane == 0) {
        const float loss_d = ((float)V_ - __expf(e0)) + ((float)V_ - __expf(e1));
        const float loss_l2 = ws[1] / (float)(B_ * T_ * D_);
        out[0] = ws[0] + DIV_W_ * loss_d + L2_W_ * loss_l2;
    }
}

extern "C" void kernel_launch(void* const* d_in, const int* in_sizes, int n_in,
                              void* d_out, int out_size, void* d_ws, size_t ws_size,
                              hipStream_t stream) {
    const float* quant = (const float*)d_in[0];
    const float* ctx   = (const float*)d_in[1];
    const float* cb    = (const float*)d_in[2];
    const int*   nidx  = (const int*)d_in[3];
    const void*  mask  = d_in[4];
    float* ws  = (float*)d_ws;
    float* out = (float*)d_out;

    // zero accumulators [0 .. 2+G*V)
    hipMemsetAsync(d_ws, 0, (2 + G_ * V_) * sizeof(float), stream);

    detect_mask_kernel<<<1, 256, 0, stream>>>((const unsigned int*)mask,
                                              (int*)(ws + WS_FLAG_IDX));
    norms_kernel<<<512, 256, 0, stream>>>(quant, ctx,
                                          ws + WS_QNORM, ws + WS_CNORM, ws + 1);
    contrastive_kernel<<<B_ * T_, 256, 0, stream>>>(
        quant, ctx, nidx, mask, (const int*)(ws + WS_FLAG_IDX),
        ws + WS_QNORM, ws + WS_CNORM, ws);
    codebook_kernel<<<512, 512, 0, stream>>>(cb, ws + 2);
    finalize_kernel<<<1, 64, 0, stream>>>(ws, out);
}